// Round 14
// baseline (2816.503 us; speedup 1.0000x reference)
//
#include <hip/hip_runtime.h>
#include <math.h>

#define N_NODES  32
#define N_HEADS  4
#define HEAD_DIM 64
#define CDIM     256           // N_HEADS * HEAD_DIM == channels
#define HWPIX    9216          // 96*96
#define ROWF4    2304          // HWPIX/4 float4 per (n,c) row
#define E_BASE   512
#define E_TOT    544           // + 32 self loops
#define NEG_SLOPE 0.2f
#define XS       257           // LDS stride for x tile (conflict-free)

#define SINKF(v) asm volatile("" :: "v"(v))
#define SINKI(v) asm volatile("" :: "v"(v))

// ---------------------------------------------------------------------------
// Kernel 1: spatial mean pool — byte-identical to R7/R12 (at BW roofline).
// ---------------------------------------------------------------------------
__global__ __launch_bounds__(256, 4) void pool_kernel(const float* __restrict__ roi,
                                                      float* __restrict__ x) {
    const int wave = threadIdx.x >> 6, lane = threadIdx.x & 63;
    const int row = blockIdx.x * 4 + wave;            // 0..8191  (n*256+c)
    const float4* p = reinterpret_cast<const float4*>(roi) + (size_t)row * ROWF4 + lane;

    float4 A[12], B[12];
    float s = 0.f;

#pragma unroll
    for (int j = 0; j < 12; ++j) A[j] = p[j * 64];              // chunk 0 -> A
#pragma unroll
    for (int j = 0; j < 12; ++j) B[j] = p[(12 + j) * 64];       // chunk 1 -> B
#pragma unroll
    for (int j = 0; j < 12; ++j) s += (A[j].x + A[j].y) + (A[j].z + A[j].w);
#pragma unroll
    for (int j = 0; j < 12; ++j) A[j] = p[(24 + j) * 64];       // chunk 2 -> A
#pragma unroll
    for (int j = 0; j < 12; ++j) s += (B[j].x + B[j].y) + (B[j].z + B[j].w);
#pragma unroll
    for (int j = 0; j < 12; ++j) s += (A[j].x + A[j].y) + (A[j].z + A[j].w);

#pragma unroll
    for (int off = 32; off; off >>= 1) s += __shfl_down(s, off);
    if (lane == 0) x[row] = s * (1.0f / (float)HWPIX);
}

// ---------------------------------------------------------------------------
// gat body, cumulative-phase gated: PH=1 stage, 2 +Wa, 3 +alphas,
// 4 +softmax+y, 5 full. PH=5,zoff=0 == R12's gat (71.3 us, passing).
// ---------------------------------------------------------------------------
template <int PH>
__device__ __forceinline__ void gat_body(const int* __restrict__ edge_index,
                                         const float* __restrict__ x,
                                         const float* __restrict__ W,
                                         const float* __restrict__ a_src,
                                         const float* __restrict__ a_dst,
                                         const float* __restrict__ gat_bias,
                                         const float* __restrict__ cls_W,
                                         const float* __restrict__ cls_b,
                                         float* __restrict__ out,
                                         int n, int zoff) {
    const int t = threadIdx.x;
    const int wavg = t >> 6, lane = t & 63;

    __shared__ float    xs[N_NODES * XS];
    __shared__ __align__(16) float asl[CDIM];
    __shared__ __align__(16) float adl[CDIM];
    __shared__ float    was[CDIM * N_HEADS];
    __shared__ float    wad[CDIM * N_HEADS];
    __shared__ float    als[N_NODES * N_HEADS];
    __shared__ float    adn[N_HEADS];
    __shared__ unsigned msegu[N_HEADS];
    __shared__ float    dseg[N_HEADS];
    __shared__ float    M[N_NODES * N_HEADS];
    __shared__ float    y[N_HEADS * CDIM];
    __shared__ float    sv[CDIM];
    __shared__ float4   red4[N_HEADS][64];
    __shared__ float    cred[8][32];

    const float* xL   = x + zoff;
    const float* WL   = W + zoff;
    const float* clsL = cls_W + zoff;
    const int*   eL   = edge_index + zoff;

    // ---------------- phase 1: upfront loads + LDS staging -----------------
    float4 xv[8];
#pragma unroll
    for (int k = 0; k < 8; ++k) xv[k] = ((const float4*)xL)[t + k * 256];
    const float asr = a_src[t], adr = a_dst[t];
    const int es0 = eL[t],       ed0 = eL[E_BASE + t];
    const int es1 = eL[256 + t], ed1 = eL[E_BASE + 256 + t];
    float4 bias4 = make_float4(0.f, 0.f, 0.f, 0.f);
    if (t < 64) bias4 = ((const float4*)gat_bias)[t];
    float cb = 0.f;
    if (t < 32) cb = cls_b[t];

#pragma unroll
    for (int k = 0; k < 8; ++k) {
        const int i = (t + k * 256) * 4, s = i >> 8, c = i & 255;
        xs[s * XS + c + 0] = xv[k].x;
        xs[s * XS + c + 1] = xv[k].y;
        xs[s * XS + c + 2] = xv[k].z;
        xs[s * XS + c + 3] = xv[k].w;
    }
    asl[t] = asr;
    adl[t] = adr;
    if (t < 128) M[t] = 0.f;
    if (t < 4) { msegu[t] = 0u; dseg[t] = 0.f; }
    __syncthreads();

    // ---------------- phase 2: Wa ------------------------------------------
    if constexpr (PH >= 2) {
        float accs[4] = {0.f, 0.f, 0.f, 0.f};
        float accd[4] = {0.f, 0.f, 0.f, 0.f};
        const float4* wr  = (const float4*)(WL + (size_t)t * CDIM);
        const float4* as4 = (const float4*)asl;
        const float4* ad4 = (const float4*)adl;
#pragma unroll 32
        for (int j = 0; j < 64; ++j) {
            const float4 w = wr[j], av = as4[j], dv = ad4[j];
            const int hd = j >> 4;
            accs[hd] += w.x * av.x + w.y * av.y + w.z * av.z + w.w * av.w;
            accd[hd] += w.x * dv.x + w.y * dv.y + w.z * dv.z + w.w * dv.w;
        }
#pragma unroll
        for (int hd = 0; hd < 4; ++hd) {
            was[t * 4 + hd] = accs[hd];
            wad[t * 4 + hd] = accd[hd];
        }
        __syncthreads();
    }

    // ---------------- phase 3: alphas --------------------------------------
    if constexpr (PH >= 3) {
        if (t < 132) {
            if (t < 128) {
                const int s = t >> 2, hd = t & 3;
                const float* xrow = &xs[s * XS];
                float acc = 0.f;
#pragma unroll 8
                for (int c = 0; c < CDIM; ++c) acc += xrow[c] * was[c * 4 + hd];
                als[t] = acc;
            } else {
                const int hd = t - 128;
                const float* xrow = &xs[n * XS];
                float acc = 0.f;
#pragma unroll 8
                for (int c = 0; c < CDIM; ++c) acc += xrow[c] * wad[c * 4 + hd];
                adn[hd] = acc;
            }
        }
        __syncthreads();
    }

    // ---------------- phase 4: softmax + y ---------------------------------
    if constexpr (PH >= 4) {
        {
            const bool sl = (t < 32) && (t == n);
#pragma unroll
            for (int hd = 0; hd < 4; ++hd) {
                float best = -INFINITY;
                if (ed0 == n) {
                    float v = als[es0 * 4 + hd] + adn[hd];
                    best = fmaxf(best, (v >= 0.f) ? v : NEG_SLOPE * v);
                }
                if (ed1 == n) {
                    float v = als[es1 * 4 + hd] + adn[hd];
                    best = fmaxf(best, (v >= 0.f) ? v : NEG_SLOPE * v);
                }
                if (sl) {
                    float v = als[n * 4 + hd] + adn[hd];
                    best = fmaxf(best, (v >= 0.f) ? v : NEG_SLOPE * v);
                }
                if (best > -INFINITY) {
                    const int iv = __float_as_int(best);
                    const unsigned key = (iv < 0) ? ~(unsigned)iv
                                                  : ((unsigned)iv | 0x80000000u);
                    atomicMax(&msegu[hd], key);
                }
            }
        }
        __syncthreads();

        float mx[4];
#pragma unroll
        for (int hd = 0; hd < 4; ++hd) {
            const unsigned key = msegu[hd];
            const int im = (key & 0x80000000u) ? (int)(key & 0x7fffffffu) : (int)~key;
            mx[hd] = __int_as_float(im);
        }

        {
            const bool sl = (t < 32) && (t == n);
#pragma unroll
            for (int hd = 0; hd < 4; ++hd) {
                if (ed0 == n) {
                    float v = als[es0 * 4 + hd] + adn[hd];
                    v = (v >= 0.f) ? v : NEG_SLOPE * v;
                    const float ex = expf(v - mx[hd]);
                    atomicAdd(&dseg[hd], ex);
                    atomicAdd(&M[es0 * 4 + hd], ex);
                }
                if (ed1 == n) {
                    float v = als[es1 * 4 + hd] + adn[hd];
                    v = (v >= 0.f) ? v : NEG_SLOPE * v;
                    const float ex = expf(v - mx[hd]);
                    atomicAdd(&dseg[hd], ex);
                    atomicAdd(&M[es1 * 4 + hd], ex);
                }
                if (sl) {
                    float v = als[n * 4 + hd] + adn[hd];
                    v = (v >= 0.f) ? v : NEG_SLOPE * v;
                    const float ex = expf(v - mx[hd]);
                    atomicAdd(&dseg[hd], ex);
                    atomicAdd(&M[n * 4 + hd], ex);
                }
            }
        }
        __syncthreads();
        if (t < 128) M[t] /= dseg[t & 3];
        __syncthreads();

        {
            const int hd = wavg;
            float a0 = 0.f, a1 = 0.f, a2 = 0.f, a3 = 0.f;
#pragma unroll
            for (int s = 0; s < N_NODES; ++s) {
                const float m = M[s * 4 + hd];
                const float* xrow = &xs[s * XS + lane];
                a0 += m * xrow[0];   a1 += m * xrow[64];
                a2 += m * xrow[128]; a3 += m * xrow[192];
            }
            y[hd * CDIM + lane]       = a0;
            y[hd * CDIM + lane + 64]  = a1;
            y[hd * CDIM + lane + 128] = a2;
            y[hd * CDIM + lane + 192] = a3;
        }
        __syncthreads();
    }

    // ---------------- phase 5: out_gat + classifier ------------------------
    if constexpr (PH >= 5) {
        {
            const int hd = lane >> 4;
            const float* yrow = &y[hd * CDIM];
            float4 acc = make_float4(0.f, 0.f, 0.f, 0.f);
#pragma unroll 16
            for (int cc = 0; cc < 64; ++cc) {
                const int c = wavg * 64 + cc;
                const float4 w4 = ((const float4*)(WL + (size_t)c * CDIM))[lane];
                const float yv = yrow[c];
                acc.x += yv * w4.x; acc.y += yv * w4.y;
                acc.z += yv * w4.z; acc.w += yv * w4.w;
            }
            red4[wavg][lane] = acc;
        }
        __syncthreads();
        if (t < 64) {
            const float4 s0 = red4[0][t], s1 = red4[1][t];
            const float4 s2 = red4[2][t], s3 = red4[3][t];
            float v0 = s0.x + s1.x + s2.x + s3.x + bias4.x;
            float v1 = s0.y + s1.y + s2.y + s3.y + bias4.y;
            float v2 = s0.z + s1.z + s2.z + s3.z + bias4.z;
            float v3 = s0.w + s1.w + s2.w + s3.w + bias4.w;
            sv[4 * t + 0] = v0 / (1.0f + expf(-v0));
            sv[4 * t + 1] = v1 / (1.0f + expf(-v1));
            sv[4 * t + 2] = v2 / (1.0f + expf(-v2));
            sv[4 * t + 3] = v3 / (1.0f + expf(-v3));
        }
        __syncthreads();

        {
            const int j = t & 31, g8 = t >> 5;
            float a = 0.f;
#pragma unroll
            for (int c0 = 0; c0 < 32; ++c0) {
                const int c = g8 * 32 + c0;
                a += sv[c] * clsL[c * 32 + j];
            }
            cred[g8][j] = a;
        }
        __syncthreads();
        if (t < 32) {
            float s2 = cb;
#pragma unroll
            for (int g2 = 0; g2 < 8; ++g2) s2 += cred[g2][t];
            out[n * 32 + t] = s2;
        }
    }

    // ---------------- anti-DCE sinks ---------------------------------------
    SINKI(es0 + ed0 + es1 + ed1);
    SINKF(bias4.x + cb);
    if constexpr (PH == 1) { SINKF(xs[t]); SINKF(asl[t]); SINKF(adl[t]); }
    if constexpr (PH == 2) { SINKF(was[t]); SINKF(wad[t]); }
    if constexpr (PH == 3) { SINKF(als[t & 127]); }
    if constexpr (PH == 4) { SINKF(y[t]); SINKF(M[t & 127]); }
}

// real kernel — behaviorally identical to R12's gat (71.3 us)
__global__ __launch_bounds__(256) void gat_real(const int* __restrict__ e,
                                                const float* __restrict__ x,
                                                const float* __restrict__ W,
                                                const float* __restrict__ as_,
                                                const float* __restrict__ ad_,
                                                const float* __restrict__ gb,
                                                const float* __restrict__ cw,
                                                const float* __restrict__ cb,
                                                float* __restrict__ o) {
    gat_body<5>(e, x, W, as_, ad_, gb, cw, cb, o, blockIdx.x, 0);
}

// probes: distinct names for rocprof, REPS sized so each lands >= ~200 us
#define DEF_PROBE(NAME, PH, REPS)                                              \
__global__ __launch_bounds__(256) void NAME(const int* __restrict__ e,         \
        const float* __restrict__ x, const float* __restrict__ W,              \
        const float* __restrict__ as_, const float* __restrict__ ad_,          \
        const float* __restrict__ gb, const float* __restrict__ cw,            \
        const float* __restrict__ cb, float* __restrict__ o) {                 \
    _Pragma("unroll 1")                                                        \
    for (int rep = 0; rep < REPS; ++rep) {                                     \
        int zoff = 0;                                                          \
        asm volatile("" : "+v"(zoff));                                         \
        gat_body<PH>(e, x, W, as_, ad_, gb, cw, cb, o, blockIdx.x, zoff);      \
        __syncthreads();                                                       \
    }                                                                          \
}

DEF_PROBE(probe_stage, 1, 256)
DEF_PROBE(probe_wa,    2, 96)
DEF_PROBE(probe_alpha, 3, 64)
DEF_PROBE(probe_smy,   4, 32)
DEF_PROBE(probe_full,  5, 16)

// ---------------------------------------------------------------------------
extern "C" void kernel_launch(void* const* d_in, const int* in_sizes, int n_in,
                              void* d_out, int out_size, void* d_ws, size_t ws_size,
                              hipStream_t stream) {
    const float* roi   = (const float*)d_in[0];
    const int*   eidx  = (const int*)d_in[1];
    const float* W     = (const float*)d_in[2];
    const float* a_src = (const float*)d_in[3];
    const float* a_dst = (const float*)d_in[4];
    const float* gbias = (const float*)d_in[5];
    const float* clsW  = (const float*)d_in[6];
    const float* clsb  = (const float*)d_in[7];
    float* out = (float*)d_out;

    float* x    = (float*)d_ws;                // [8192] floats
    float* out2 = x + 8192;                    // probe scratch (inert)

    pool_kernel<<<(N_NODES * CDIM) / 4, 256, 0, stream>>>(roi, x);
    gat_real<<<N_NODES, 256, 0, stream>>>(eidx, x, W, a_src, a_dst,
                                          gbias, clsW, clsb, out);
    // ---- ablation probes (inert, write only to out2) ----------------------
    probe_stage<<<N_NODES, 256, 0, stream>>>(eidx, x, W, a_src, a_dst,
                                             gbias, clsW, clsb, out2);
    probe_wa<<<N_NODES, 256, 0, stream>>>(eidx, x, W, a_src, a_dst,
                                          gbias, clsW, clsb, out2);
    probe_alpha<<<N_NODES, 256, 0, stream>>>(eidx, x, W, a_src, a_dst,
                                             gbias, clsW, clsb, out2);
    probe_smy<<<N_NODES, 256, 0, stream>>>(eidx, x, W, a_src, a_dst,
                                           gbias, clsW, clsb, out2);
    probe_full<<<N_NODES, 256, 0, stream>>>(eidx, x, W, a_src, a_dst,
                                            gbias, clsW, clsb, out2);
}

// Round 15
// 64.453 us; speedup vs baseline: 43.6987x; 43.6987x over previous
//
#include <hip/hip_runtime.h>
#include <math.h>

#define N_NODES  32
#define N_HEADS  4
#define HEAD_DIM 64
#define CDIM     256           // N_HEADS * HEAD_DIM == channels
#define HWPIX    9216          // 96*96
#define ROWF4    2304          // HWPIX/4 float4 per (n,c) row
#define E_BASE   512
#define E_TOT    544           // + 32 self loops
#define NEG_SLOPE 0.2f
#define XS       257           // LDS stride for x tile (conflict-free)
#define POOL_BLOCKS 2048

// ---------------------------------------------------------------------------
// Kernel 1: spatial mean pool (R7 body, byte-identical — at BW roofline) plus
// ONE prep block (blockIdx == 2048) computing Wa = W.a_src / W.a_dst into the
// workspace. The prep block is x-independent and hides entirely under the
// pool's ~44 us memory shadow.
// ---------------------------------------------------------------------------
__global__ __launch_bounds__(256, 4) void pool_kernel(const float* __restrict__ roi,
                                                      const float* __restrict__ W,
                                                      const float* __restrict__ a_src,
                                                      const float* __restrict__ a_dst,
                                                      float* __restrict__ x,
                                                      float* __restrict__ was_g,
                                                      float* __restrict__ wad_g) {
    if (blockIdx.x == POOL_BLOCKS) {                  // ---- hidden prep block
        const int t = threadIdx.x;                    // row c = t
        float accs[4] = {0.f, 0.f, 0.f, 0.f};
        float accd[4] = {0.f, 0.f, 0.f, 0.f};
        const float4* wr  = (const float4*)(W + (size_t)t * CDIM);
        const float4* as4 = (const float4*)a_src;
        const float4* ad4 = (const float4*)a_dst;
#pragma unroll 16
        for (int j = 0; j < 64; ++j) {                // j -> head j>>4
            const float4 w = wr[j], av = as4[j], dv = ad4[j];
            const int hd = j >> 4;
            accs[hd] += w.x * av.x + w.y * av.y + w.z * av.z + w.w * av.w;
            accd[hd] += w.x * dv.x + w.y * dv.y + w.z * dv.z + w.w * dv.w;
        }
#pragma unroll
        for (int hd = 0; hd < 4; ++hd) {
            was_g[t * 4 + hd] = accs[hd];
            wad_g[t * 4 + hd] = accd[hd];
        }
        return;
    }

    const int wave = threadIdx.x >> 6, lane = threadIdx.x & 63;
    const int row = blockIdx.x * 4 + wave;            // 0..8191  (n*256+c)
    const float4* p = reinterpret_cast<const float4*>(roi) + (size_t)row * ROWF4 + lane;

    float4 A[12], B[12];
    float s = 0.f;

#pragma unroll
    for (int j = 0; j < 12; ++j) A[j] = p[j * 64];              // chunk 0 -> A
#pragma unroll
    for (int j = 0; j < 12; ++j) B[j] = p[(12 + j) * 64];       // chunk 1 -> B
#pragma unroll
    for (int j = 0; j < 12; ++j) s += (A[j].x + A[j].y) + (A[j].z + A[j].w);
#pragma unroll
    for (int j = 0; j < 12; ++j) A[j] = p[(24 + j) * 64];       // chunk 2 -> A
#pragma unroll
    for (int j = 0; j < 12; ++j) s += (B[j].x + B[j].y) + (B[j].z + B[j].w);
#pragma unroll
    for (int j = 0; j < 12; ++j) s += (A[j].x + A[j].y) + (A[j].z + A[j].w);

#pragma unroll
    for (int off = 32; off; off >>= 1) s += __shfl_down(s, off);
    if (lane == 0) x[row] = s * (1.0f / (float)HWPIX);
}

// ---------------------------------------------------------------------------
// Kernel 2: GAT + classifier, v5.
// - Wa phase REMOVED (the R14-ablation 8 us hog): was/wad loaded precomputed
//   as one coalesced float4/thread batch merged into the upfront loads.
// - denominator folded into the y loop (y = sum(m x)/sum(m)), deleting the
//   dseg atomics, the normalize pass, and 2 barriers (9 -> 7).
// - everything else identical to R12 (71.3 us baseline).
// ---------------------------------------------------------------------------
__global__ __launch_bounds__(256) void gat_kernel(const int* __restrict__ edge_index,
                                                  const float* __restrict__ x,
                                                  const float* __restrict__ was_g,
                                                  const float* __restrict__ wad_g,
                                                  const float* __restrict__ W,
                                                  const float* __restrict__ gat_bias,
                                                  const float* __restrict__ cls_W,
                                                  const float* __restrict__ cls_b,
                                                  float* __restrict__ out) {
    const int n = blockIdx.x;                         // dst node this block owns
    const int t = threadIdx.x;
    const int wavg = t >> 6, lane = t & 63;

    __shared__ float    xs[N_NODES * XS];             // 32,896 B
    __shared__ float    was[CDIM * N_HEADS];          // W . a_src  [c][hd]
    __shared__ float    wad[CDIM * N_HEADS];          // W . a_dst  [c][hd]
    __shared__ float    als[N_NODES * N_HEADS];       // alpha_src, all nodes
    __shared__ float    adn[N_HEADS];                 // alpha_dst, own node
    __shared__ unsigned msegu[N_HEADS];
    __shared__ float    M[N_NODES * N_HEADS];         // attention row [s][hd]
    __shared__ float    y[N_HEADS * CDIM];
    __shared__ float    sv[CDIM];
    __shared__ float4   red4[N_HEADS][64];            // out_gat partials
    __shared__ float    cred[8][32];                  // classifier partials

    // ---- issue ALL independent global loads up front (one flight batch) ---
    float4 xv[8];
#pragma unroll
    for (int k = 0; k < 8; ++k) xv[k] = ((const float4*)x)[t + k * 256];
    const float4 wasv = ((const float4*)was_g)[t];    // c=t, hd=0..3
    const float4 wadv = ((const float4*)wad_g)[t];
    const int es0 = edge_index[t],       ed0 = edge_index[E_BASE + t];
    const int es1 = edge_index[256 + t], ed1 = edge_index[E_BASE + 256 + t];
    float4 bias4 = make_float4(0.f, 0.f, 0.f, 0.f);
    if (t < 64) bias4 = ((const float4*)gat_bias)[t];
    float cb = 0.f;
    if (t < 32) cb = cls_b[t];

    // ---- LDS staging -------------------------------------------------------
#pragma unroll
    for (int k = 0; k < 8; ++k) {
        const int i = (t + k * 256) * 4, s = i >> 8, c = i & 255;
        xs[s * XS + c + 0] = xv[k].x;
        xs[s * XS + c + 1] = xv[k].y;
        xs[s * XS + c + 2] = xv[k].z;
        xs[s * XS + c + 3] = xv[k].w;
    }
    ((float4*)was)[t] = wasv;
    ((float4*)wad)[t] = wadv;
    if (t < 128) M[t] = 0.f;
    if (t < 4) msegu[t] = 0u;
    __syncthreads();                                  // B1

    // ---- alphas: als[s,hd] = xs[s,:].was[:,hd]; adn = xs[n,:].wad[:,hd] ----
    if (t < 132) {
        if (t < 128) {
            const int s = t >> 2, hd = t & 3;
            const float* xrow = &xs[s * XS];
            float acc = 0.f;
#pragma unroll 8
            for (int c = 0; c < CDIM; ++c) acc += xrow[c] * was[c * 4 + hd];
            als[t] = acc;
        } else {
            const int hd = t - 128;
            const float* xrow = &xs[n * XS];
            float acc = 0.f;
#pragma unroll 8
            for (int c = 0; c < CDIM; ++c) acc += xrow[c] * wad[c * 4 + hd];
            adn[hd] = acc;
        }
    }
    __syncthreads();                                  // B2

    // ---- pass A: segment max (edges in registers, monotone-uint atomicMax) -
    {
        const bool sl = (t < 32) && (t == n);         // self loop (s0=t,d=t)
#pragma unroll
        for (int hd = 0; hd < 4; ++hd) {
            float best = -INFINITY;
            if (ed0 == n) {
                float v = als[es0 * 4 + hd] + adn[hd];
                best = fmaxf(best, (v >= 0.f) ? v : NEG_SLOPE * v);
            }
            if (ed1 == n) {
                float v = als[es1 * 4 + hd] + adn[hd];
                best = fmaxf(best, (v >= 0.f) ? v : NEG_SLOPE * v);
            }
            if (sl) {
                float v = als[n * 4 + hd] + adn[hd];
                best = fmaxf(best, (v >= 0.f) ? v : NEG_SLOPE * v);
            }
            if (best > -INFINITY) {
                const int iv = __float_as_int(best);
                const unsigned key = (iv < 0) ? ~(unsigned)iv
                                              : ((unsigned)iv | 0x80000000u);
                atomicMax(&msegu[hd], key);
            }
        }
    }
    __syncthreads();                                  // B3

    float mx[4];
#pragma unroll
    for (int hd = 0; hd < 4; ++hd) {
        const unsigned key = msegu[hd];
        const int im = (key & 0x80000000u) ? (int)(key & 0x7fffffffu) : (int)~key;
        mx[hd] = __int_as_float(im);
    }

    // ---- pass B: exp + unnormalized attention row (no dseg — folded in y) --
    {
        const bool sl = (t < 32) && (t == n);
#pragma unroll
        for (int hd = 0; hd < 4; ++hd) {
            if (ed0 == n) {
                float v = als[es0 * 4 + hd] + adn[hd];
                v = (v >= 0.f) ? v : NEG_SLOPE * v;
                atomicAdd(&M[es0 * 4 + hd], expf(v - mx[hd]));
            }
            if (ed1 == n) {
                float v = als[es1 * 4 + hd] + adn[hd];
                v = (v >= 0.f) ? v : NEG_SLOPE * v;
                atomicAdd(&M[es1 * 4 + hd], expf(v - mx[hd]));
            }
            if (sl) {
                float v = als[n * 4 + hd] + adn[hd];
                v = (v >= 0.f) ? v : NEG_SLOPE * v;
                atomicAdd(&M[n * 4 + hd], expf(v - mx[hd]));
            }
        }
    }
    __syncthreads();                                  // B4

    // ---- y[hd,c] = (sum_s m xs[s,c]) / (sum_s m)  (denom folded in) --------
    {
        const int hd = wavg;
        float a0 = 0.f, a1 = 0.f, a2 = 0.f, a3 = 0.f, msum = 0.f;
#pragma unroll
        for (int s = 0; s < N_NODES; ++s) {
            const float m = M[s * 4 + hd];            // wave-uniform broadcast
            msum += m;
            const float* xrow = &xs[s * XS + lane];
            a0 += m * xrow[0];   a1 += m * xrow[64];
            a2 += m * xrow[128]; a3 += m * xrow[192];
        }
        const float rd = 1.0f / msum;                 // denom = sum of all exps
        y[hd * CDIM + lane]       = a0 * rd;
        y[hd * CDIM + lane + 64]  = a1 * rd;
        y[hd * CDIM + lane + 128] = a2 * rd;
        y[hd * CDIM + lane + 192] = a3 * rd;
    }
    __syncthreads();                                  // B5

    // ---- out_gat: coalesced float4 W reads + 4-way LDS reduce --------------
    {
        const int hd = lane >> 4;
        const float* yrow = &y[hd * CDIM];
        float4 acc = make_float4(0.f, 0.f, 0.f, 0.f);
#pragma unroll 16
        for (int cc = 0; cc < 64; ++cc) {
            const int c = wavg * 64 + cc;
            const float4 w4 = ((const float4*)(W + (size_t)c * CDIM))[lane];
            const float yv = yrow[c];
            acc.x += yv * w4.x; acc.y += yv * w4.y;
            acc.z += yv * w4.z; acc.w += yv * w4.w;
        }
        red4[wavg][lane] = acc;
    }
    __syncthreads();                                  // B6
    if (t < 64) {
        const float4 s0 = red4[0][t], s1 = red4[1][t];
        const float4 s2 = red4[2][t], s3 = red4[3][t];
        float v0 = s0.x + s1.x + s2.x + s3.x + bias4.x;
        float v1 = s0.y + s1.y + s2.y + s3.y + bias4.y;
        float v2 = s0.z + s1.z + s2.z + s3.z + bias4.z;
        float v3 = s0.w + s1.w + s2.w + s3.w + bias4.w;
        sv[4 * t + 0] = v0 / (1.0f + expf(-v0));
        sv[4 * t + 1] = v1 / (1.0f + expf(-v1));
        sv[4 * t + 2] = v2 / (1.0f + expf(-v2));
        sv[4 * t + 3] = v3 / (1.0f + expf(-v3));
    }
    __syncthreads();                                  // B7

    // ---- classifier: 8 groups x 32 cols, fully unrolled --------------------
    {
        const int j = t & 31, g8 = t >> 5;
        float a = 0.f;
#pragma unroll
        for (int c0 = 0; c0 < 32; ++c0) {
            const int c = g8 * 32 + c0;
            a += sv[c] * cls_W[c * 32 + j];           // coalesced
        }
        cred[g8][j] = a;
    }
    __syncthreads();
    if (t < 32) {
        float s2 = cb;
#pragma unroll
        for (int g2 = 0; g2 < 8; ++g2) s2 += cred[g2][t];
        out[n * 32 + t] = s2;
    }
}

// ---------------------------------------------------------------------------
extern "C" void kernel_launch(void* const* d_in, const int* in_sizes, int n_in,
                              void* d_out, int out_size, void* d_ws, size_t ws_size,
                              hipStream_t stream) {
    const float* roi   = (const float*)d_in[0];
    const int*   eidx  = (const int*)d_in[1];
    const float* W     = (const float*)d_in[2];
    const float* a_src = (const float*)d_in[3];
    const float* a_dst = (const float*)d_in[4];
    const float* gbias = (const float*)d_in[5];
    const float* clsW  = (const float*)d_in[6];
    const float* clsb  = (const float*)d_in[7];
    float* out = (float*)d_out;

    float* x     = (float*)d_ws;               // [8192] floats
    float* was_g = x + 8192;                   // [1024]
    float* wad_g = was_g + 1024;               // [1024]

    pool_kernel<<<POOL_BLOCKS + 1, 256, 0, stream>>>(roi, W, a_src, a_dst,
                                                     x, was_g, wad_g);
    gat_kernel<<<N_NODES, 256, 0, stream>>>(eidx, x, was_g, wad_g, W,
                                            gbias, clsW, clsb, out);
}

// Round 16
// 63.532 us; speedup vs baseline: 44.3322x; 1.0145x over previous
//
#include <hip/hip_runtime.h>
#include <math.h>

#define N_NODES  32
#define N_HEADS  4
#define CDIM     256           // N_HEADS * HEAD_DIM == channels
#define HWPIX    9216          // 96*96
#define ROWF4    2304          // HWPIX/4 float4 per (n,c) row
#define E_BASE   512
#define E_TOT    544           // + 32 self loops
#define NEG_SLOPE 0.2f
#define XS       257           // LDS stride for x tile (conflict-free)
#define POOL_BLOCKS 2048

// ---------------------------------------------------------------------------
// Kernel 1: spatial mean pool (R7 body, byte-identical — at BW roofline) plus
// ONE prep block computing Wa = W.a_src / W.a_dst (hidden under pool shadow).
// ---------------------------------------------------------------------------
__global__ __launch_bounds__(256, 4) void pool_kernel(const float* __restrict__ roi,
                                                      const float* __restrict__ W,
                                                      const float* __restrict__ a_src,
                                                      const float* __restrict__ a_dst,
                                                      float* __restrict__ x,
                                                      float* __restrict__ was_g,
                                                      float* __restrict__ wad_g) {
    if (blockIdx.x == POOL_BLOCKS) {                  // ---- hidden prep block
        const int t = threadIdx.x;                    // row c = t
        float accs[4] = {0.f, 0.f, 0.f, 0.f};
        float accd[4] = {0.f, 0.f, 0.f, 0.f};
        const float4* wr  = (const float4*)(W + (size_t)t * CDIM);
        const float4* as4 = (const float4*)a_src;
        const float4* ad4 = (const float4*)a_dst;
#pragma unroll 16
        for (int j = 0; j < 64; ++j) {                // j -> head j>>4
            const float4 w = wr[j], av = as4[j], dv = ad4[j];
            const int hd = j >> 4;
            accs[hd] += w.x * av.x + w.y * av.y + w.z * av.z + w.w * av.w;
            accd[hd] += w.x * dv.x + w.y * dv.y + w.z * dv.z + w.w * dv.w;
        }
#pragma unroll
        for (int hd = 0; hd < 4; ++hd) {
            was_g[t * 4 + hd] = accs[hd];
            wad_g[t * 4 + hd] = accd[hd];
        }
        return;
    }

    const int wave = threadIdx.x >> 6, lane = threadIdx.x & 63;
    const int row = blockIdx.x * 4 + wave;            // 0..8191  (n*256+c)
    const float4* p = reinterpret_cast<const float4*>(roi) + (size_t)row * ROWF4 + lane;

    float4 A[12], B[12];
    float s = 0.f;

#pragma unroll
    for (int j = 0; j < 12; ++j) A[j] = p[j * 64];              // chunk 0 -> A
#pragma unroll
    for (int j = 0; j < 12; ++j) B[j] = p[(12 + j) * 64];       // chunk 1 -> B
#pragma unroll
    for (int j = 0; j < 12; ++j) s += (A[j].x + A[j].y) + (A[j].z + A[j].w);
#pragma unroll
    for (int j = 0; j < 12; ++j) A[j] = p[(24 + j) * 64];       // chunk 2 -> A
#pragma unroll
    for (int j = 0; j < 12; ++j) s += (B[j].x + B[j].y) + (B[j].z + B[j].w);
#pragma unroll
    for (int j = 0; j < 12; ++j) s += (A[j].x + A[j].y) + (A[j].z + A[j].w);

#pragma unroll
    for (int off = 32; off; off >>= 1) s += __shfl_down(s, off);
    if (lane == 0) x[row] = s * (1.0f / (float)HWPIX);
}

// ---------------------------------------------------------------------------
// Kernel 2: GAT + classifier, v6 — 1024 threads (16 waves) for TLP.
// out_gat: 16 W rows/wave, 16 float4/lane in ONE vmcnt batch, issued early
// (right after pass B) so latency hides under the y phase. cls_W slice
// loaded upfront. red4/cred overlay dead xs (arena). 32 blocks (1/CU).
// ---------------------------------------------------------------------------
__global__ __launch_bounds__(1024, 4) void gat_kernel(const int* __restrict__ edge_index,
                                                      const float* __restrict__ x,
                                                      const float* __restrict__ was_g,
                                                      const float* __restrict__ wad_g,
                                                      const float* __restrict__ W,
                                                      const float* __restrict__ gat_bias,
                                                      const float* __restrict__ cls_W,
                                                      const float* __restrict__ cls_b,
                                                      float* __restrict__ out) {
    const int n = blockIdx.x;                         // dst node this block owns
    const int t = threadIdx.x;
    const int wv = t >> 6, ln = t & 63;

    __shared__ __align__(16) char arena[N_NODES * XS * 4];  // 32,896 B
    float*  xs   = (float*)arena;                     // x tile [32][257]
    float4* red4 = (float4*)arena;                    // [16][64] after xs dies
    float*  cred = (float*)(arena + 16384);           // [32][32] after xs dies
    __shared__ float    was[CDIM * N_HEADS];          // [c][hd]
    __shared__ float    wad[CDIM * N_HEADS];
    __shared__ float    als[N_NODES * N_HEADS];
    __shared__ float    adn[N_HEADS];
    __shared__ unsigned msegu[N_HEADS];
    __shared__ float    M[N_NODES * N_HEADS];
    __shared__ float    y[N_HEADS * CDIM];
    __shared__ float    sv[CDIM];

    // ---- upfront independent global loads ---------------------------------
    const float4 xv0 = ((const float4*)x)[t];         // 2048 float4 total
    const float4 xv1 = ((const float4*)x)[t + 1024];
    float4 wasv = make_float4(0.f,0.f,0.f,0.f), wadv = wasv;
    if (t < 256) {
        wasv = ((const float4*)was_g)[t];
        wadv = ((const float4*)wad_g)[t];
    }
    int es0 = 0, ed0 = -1;
    if (t < E_BASE) { es0 = edge_index[t]; ed0 = edge_index[E_BASE + t]; }
    float4 bias4 = make_float4(0.f,0.f,0.f,0.f);
    if (t < 64) bias4 = ((const float4*)gat_bias)[t];
    float cb = 0.f;
    if (t < 32) cb = cls_b[t];
    float cw[8];                                      // cls_W slice: c in [8g,8g+8)
    {
        const int k = t & 31, g = t >> 5;
#pragma unroll
        for (int i = 0; i < 8; ++i) cw[i] = cls_W[(g * 8 + i) * 32 + k];
    }

    // ---- LDS staging -------------------------------------------------------
    {
        int i = t * 4, s = i >> 8, c = i & 255;
        xs[s * XS + c + 0] = xv0.x; xs[s * XS + c + 1] = xv0.y;
        xs[s * XS + c + 2] = xv0.z; xs[s * XS + c + 3] = xv0.w;
        i = (t + 1024) * 4; s = i >> 8; c = i & 255;
        xs[s * XS + c + 0] = xv1.x; xs[s * XS + c + 1] = xv1.y;
        xs[s * XS + c + 2] = xv1.z; xs[s * XS + c + 3] = xv1.w;
    }
    if (t < 256) { ((float4*)was)[t] = wasv; ((float4*)wad)[t] = wadv; }
    if (t < 128) M[t] = 0.f;
    if (t < 4)   msegu[t] = 0u;
    __syncthreads();                                  // B1

    // ---- alphas, 4-way split + shfl reduce ---------------------------------
    if (t < 528) {
        const int q = t & 3;
        const int s  = (t < 512) ? (t >> 4) : n;
        const int hd = (t < 512) ? ((t >> 2) & 3) : ((t - 512) >> 2);
        const float* xrow = &xs[s * XS + q * 64];
        const float* wvp  = (t < 512) ? &was[q * 256 + hd] : &wad[q * 256 + hd];
        float acc = 0.f;
#pragma unroll 16
        for (int c = 0; c < 64; ++c) acc += xrow[c] * wvp[c * 4];
        acc += __shfl_down(acc, 2);
        acc += __shfl_down(acc, 1);
        if (q == 0) {
            if (t < 512) als[(t >> 4) * 4 + hd] = acc;
            else         adn[hd] = acc;
        }
    }
    __syncthreads();                                  // B2

    // ---- pass A: segment max (one edge per thread) -------------------------
    if (t < E_TOT) {
        const int s0 = (t < E_BASE) ? es0 : (t - E_BASE);
        const int d  = (t < E_BASE) ? ed0 : (t - E_BASE);
        if (d == n) {
#pragma unroll
            for (int hd = 0; hd < 4; ++hd) {
                float v = als[s0 * 4 + hd] + adn[hd];
                v = (v >= 0.f) ? v : NEG_SLOPE * v;
                const int iv = __float_as_int(v);
                const unsigned key = (iv < 0) ? ~(unsigned)iv
                                              : ((unsigned)iv | 0x80000000u);
                atomicMax(&msegu[hd], key);
            }
        }
    }
    __syncthreads();                                  // B3

    float mx[4];
#pragma unroll
    for (int hd = 0; hd < 4; ++hd) {
        const unsigned key = msegu[hd];
        const int im = (key & 0x80000000u) ? (int)(key & 0x7fffffffu) : (int)~key;
        mx[hd] = __int_as_float(im);
    }

    // ---- pass B: exp + unnormalized attention row --------------------------
    if (t < E_TOT) {
        const int s0 = (t < E_BASE) ? es0 : (t - E_BASE);
        const int d  = (t < E_BASE) ? ed0 : (t - E_BASE);
        if (d == n) {
#pragma unroll
            for (int hd = 0; hd < 4; ++hd) {
                float v = als[s0 * 4 + hd] + adn[hd];
                v = (v >= 0.f) ? v : NEG_SLOPE * v;
                atomicAdd(&M[s0 * 4 + hd], expf(v - mx[hd]));
            }
        }
    }
    __syncthreads();                                  // B4

    // ---- issue W tile loads NOW (independent of y): one vmcnt batch --------
    float4 wreg[16];                                  // wave wv: rows 16wv..16wv+15
#pragma unroll
    for (int r = 0; r < 16; ++r)
        wreg[r] = ((const float4*)(W + (size_t)(wv * 16 + r) * CDIM))[ln];

    // ---- y[hd,c] = sum_s M xs / sum_s M  (denom folded) --------------------
    {
        const int hd = t >> 8, c = t & 255;
        float acc = 0.f, msum = 0.f;
#pragma unroll
        for (int s = 0; s < N_NODES; ++s) {
            const float m = M[s * 4 + hd];
            msum += m;
            acc += m * xs[s * XS + c];
        }
        y[hd * CDIM + c] = acc / msum;
    }
    __syncthreads();                                  // B5 (xs dead; arena reused)

    // ---- out_gat: wave wv covers c rows [16wv,16wv+16); lane -> 4 cols -----
    {
        const int hd = ln >> 4;                       // cols 4ln..4ln+3, head
        float4 acc = make_float4(0.f, 0.f, 0.f, 0.f);
#pragma unroll
        for (int r = 0; r < 16; ++r) {
            const float yv = y[hd * CDIM + wv * 16 + r];
            acc.x += yv * wreg[r].x; acc.y += yv * wreg[r].y;
            acc.z += yv * wreg[r].z; acc.w += yv * wreg[r].w;
        }
        red4[wv * 64 + ln] = acc;
    }
    __syncthreads();                                  // B6
    if (t < 64) {
        float4 a = bias4;
#pragma unroll
        for (int g = 0; g < 16; ++g) {
            const float4 r = red4[g * 64 + t];
            a.x += r.x; a.y += r.y; a.z += r.z; a.w += r.w;
        }
        sv[4 * t + 0] = a.x / (1.0f + expf(-a.x));
        sv[4 * t + 1] = a.y / (1.0f + expf(-a.y));
        sv[4 * t + 2] = a.z / (1.0f + expf(-a.z));
        sv[4 * t + 3] = a.w / (1.0f + expf(-a.w));
    }
    __syncthreads();                                  // B7

    // ---- classifier: 32 groups x 32 cols, cls_W already in regs ------------
    {
        const int k = t & 31, g = t >> 5;
        float a = 0.f;
#pragma unroll
        for (int i = 0; i < 8; ++i) a += sv[g * 8 + i] * cw[i];
        cred[g * 32 + k] = a;
    }
    __syncthreads();                                  // B8
    if (t < 32) {
        float s2 = cb;
#pragma unroll
        for (int g = 0; g < 32; ++g) s2 += cred[g * 32 + t];
        out[n * 32 + t] = s2;
    }
}

// ---------------------------------------------------------------------------
extern "C" void kernel_launch(void* const* d_in, const int* in_sizes, int n_in,
                              void* d_out, int out_size, void* d_ws, size_t ws_size,
                              hipStream_t stream) {
    const float* roi   = (const float*)d_in[0];
    const int*   eidx  = (const int*)d_in[1];
    const float* W     = (const float*)d_in[2];
    const float* a_src = (const float*)d_in[3];
    const float* a_dst = (const float*)d_in[4];
    const float* gbias = (const float*)d_in[5];
    const float* clsW  = (const float*)d_in[6];
    const float* clsb  = (const float*)d_in[7];
    float* out = (float*)d_out;

    float* x     = (float*)d_ws;               // [8192] floats
    float* was_g = x + 8192;                   // [1024]
    float* wad_g = was_g + 1024;               // [1024]

    pool_kernel<<<POOL_BLOCKS + 1, 256, 0, stream>>>(roi, W, a_src, a_dst,
                                                     x, was_g, wad_g);
    gat_kernel<<<N_NODES, 1024, 0, stream>>>(eidx, x, was_g, wad_g, W,
                                             gbias, clsW, clsb, out);
}

// Round 17
// 59.172 us; speedup vs baseline: 47.5984x; 1.0737x over previous
//
#include <hip/hip_runtime.h>
#include <math.h>

#define N_NODES  32
#define N_HEADS  4
#define CDIM     256           // N_HEADS * HEAD_DIM == channels
#define HWPIX    9216          // 96*96
#define ROWF4    2304          // HWPIX/4 float4 per (n,c) row
#define E_BASE   512
#define E_TOT    544           // + 32 self loops
#define NEG_SLOPE 0.2f
#define XS       257           // LDS stride for H tile (conflict-free)

// ---------------------------------------------------------------------------
// Kernel 1: spatial mean pool — byte-identical to R7 (at BW roofline).
// ---------------------------------------------------------------------------
__global__ __launch_bounds__(256, 4) void pool_kernel(const float* __restrict__ roi,
                                                      float* __restrict__ x) {
    const int wave = threadIdx.x >> 6, lane = threadIdx.x & 63;
    const int row = blockIdx.x * 4 + wave;            // 0..8191  (n*256+c)
    const float4* p = reinterpret_cast<const float4*>(roi) + (size_t)row * ROWF4 + lane;

    float4 A[12], B[12];
    float s = 0.f;

#pragma unroll
    for (int j = 0; j < 12; ++j) A[j] = p[j * 64];              // chunk 0 -> A
#pragma unroll
    for (int j = 0; j < 12; ++j) B[j] = p[(12 + j) * 64];       // chunk 1 -> B
#pragma unroll
    for (int j = 0; j < 12; ++j) s += (A[j].x + A[j].y) + (A[j].z + A[j].w);
#pragma unroll
    for (int j = 0; j < 12; ++j) A[j] = p[(24 + j) * 64];       // chunk 2 -> A
#pragma unroll
    for (int j = 0; j < 12; ++j) s += (B[j].x + B[j].y) + (B[j].z + B[j].w);
#pragma unroll
    for (int j = 0; j < 12; ++j) s += (A[j].x + A[j].y) + (A[j].z + A[j].w);

#pragma unroll
    for (int off = 32; off; off >>= 1) s += __shfl_down(s, off);
    if (lane == 0) x[row] = s * (1.0f / (float)HWPIX);
}

// ---------------------------------------------------------------------------
// Kernel 2: H = x @ W  (32x256). 256 blocks: block b -> node s = b>>3,
// col slice [32(b&7), +32). Each block reads a DISJOINT 32 KB W slice —
// W is read once across the whole grid (256 KB total, vs 8 MB in R16).
// 8-way c-chunk split per output element + LDS reduce.
// ---------------------------------------------------------------------------
__global__ __launch_bounds__(256) void h_kernel(const float* __restrict__ x,
                                                const float* __restrict__ W,
                                                float* __restrict__ H) {
    const int b = blockIdx.x;
    const int s = b >> 3, colbase = (b & 7) * 32;
    const int t = threadIdx.x;
    __shared__ float xrow[CDIM];
    __shared__ float part[8][32];

    xrow[t] = x[s * CDIM + t];                        // coalesced 1 KB
    __syncthreads();

    const int j = t & 31, q = t >> 5;                 // col j, c-chunk q
    const float* wp = W + (size_t)(q * 32) * CDIM + colbase + j;
    const float* xq = &xrow[q * 32];
    float acc = 0.f;
#pragma unroll
    for (int i = 0; i < 32; ++i)                      // 32 loads, one batch
        acc += xq[i] * wp[(size_t)i * CDIM];
    part[q][j] = acc;
    __syncthreads();

    if (t < 32) {
        float a = 0.f;
#pragma unroll
        for (int qq = 0; qq < 8; ++qq) a += part[qq][t];
        H[s * CDIM + colbase + t] = a;
    }
}

// ---------------------------------------------------------------------------
// Kernel 3: GAT + classifier, v7 — completely W-free.
// alphas from H (als = H.a_src); aggregation = sum_s M*H[s] with folded
// denominator (y and out_gat collapse into ONE LDS-only phase). Global
// traffic: H 32 KB + cls_W 32 KB + a/edges/bias ~4 KB, all L2/L3-hot.
// ---------------------------------------------------------------------------
__global__ __launch_bounds__(256) void gat_kernel(const int* __restrict__ edge_index,
                                                  const float* __restrict__ H,
                                                  const float* __restrict__ a_src,
                                                  const float* __restrict__ a_dst,
                                                  const float* __restrict__ gat_bias,
                                                  const float* __restrict__ cls_W,
                                                  const float* __restrict__ cls_b,
                                                  float* __restrict__ out) {
    const int n = blockIdx.x;                         // dst node this block owns
    const int t = threadIdx.x;

    __shared__ float    hs[N_NODES * XS];             // H tile, stride 257
    __shared__ __align__(16) float asl[CDIM];         // a_src flat
    __shared__ __align__(16) float adl[CDIM];         // a_dst flat
    __shared__ float    als[N_NODES * N_HEADS];       // alpha_src, all nodes
    __shared__ float    adn[N_HEADS];                 // alpha_dst, own node
    __shared__ unsigned msegu[N_HEADS];
    __shared__ float    M[N_NODES * N_HEADS];         // attention row [s][hd]
    __shared__ float    sv[CDIM];                     // silu(out_gat)
    __shared__ float    cred[8][32];                  // classifier partials

    // ---- upfront independent global loads (one flight batch) --------------
    float4 hv[8];
#pragma unroll
    for (int k = 0; k < 8; ++k) hv[k] = ((const float4*)H)[t + k * 256];
    const float asr = a_src[t], adr = a_dst[t];
    const float gb = gat_bias[t];
    const int es0 = edge_index[t],       ed0 = edge_index[E_BASE + t];
    const int es1 = edge_index[256 + t], ed1 = edge_index[E_BASE + 256 + t];
    float cb = 0.f;
    if (t < 32) cb = cls_b[t];
    float cw[32];                                     // cls_W[c=32g+i][j=t&31]
    {
        const int j = t & 31, g = t >> 5;
#pragma unroll
        for (int i = 0; i < 32; ++i) cw[i] = cls_W[(g * 32 + i) * 32 + j];
    }

    // ---- LDS staging -------------------------------------------------------
#pragma unroll
    for (int k = 0; k < 8; ++k) {
        const int i = (t + k * 256) * 4, s = i >> 8, c = i & 255;
        hs[s * XS + c + 0] = hv[k].x;
        hs[s * XS + c + 1] = hv[k].y;
        hs[s * XS + c + 2] = hv[k].z;
        hs[s * XS + c + 3] = hv[k].w;
    }
    asl[t] = asr;
    adl[t] = adr;
    if (t < 128) M[t] = 0.f;
    if (t < 4)   msegu[t] = 0u;
    __syncthreads();                                  // B1

    // ---- alphas from H: als[s,hd] = H[s,hd*64:].a_src[hd]; adn likewise ----
    if (t < 132) {
        if (t < 128) {
            const int s = t >> 2, hd = t & 3;
            const float* hrow = &hs[s * XS + hd * 64];
            const float* av   = &asl[hd * 64];
            float acc = 0.f;
#pragma unroll 16
            for (int f = 0; f < 64; ++f) acc += hrow[f] * av[f];
            als[t] = acc;
        } else {
            const int hd = t - 128;
            const float* hrow = &hs[n * XS + hd * 64];
            const float* av   = &adl[hd * 64];
            float acc = 0.f;
#pragma unroll 16
            for (int f = 0; f < 64; ++f) acc += hrow[f] * av[f];
            adn[hd] = acc;
        }
    }
    __syncthreads();                                  // B2

    // ---- pass A: segment max (edges in registers, monotone-uint atomicMax) -
    {
        const bool sl = (t < 32) && (t == n);         // self loop (s0=t,d=t)
#pragma unroll
        for (int hd = 0; hd < 4; ++hd) {
            float best = -INFINITY;
            if (ed0 == n) {
                float v = als[es0 * 4 + hd] + adn[hd];
                best = fmaxf(best, (v >= 0.f) ? v : NEG_SLOPE * v);
            }
            if (ed1 == n) {
                float v = als[es1 * 4 + hd] + adn[hd];
                best = fmaxf(best, (v >= 0.f) ? v : NEG_SLOPE * v);
            }
            if (sl) {
                float v = als[n * 4 + hd] + adn[hd];
                best = fmaxf(best, (v >= 0.f) ? v : NEG_SLOPE * v);
            }
            if (best > -INFINITY) {
                const int iv = __float_as_int(best);
                const unsigned key = (iv < 0) ? ~(unsigned)iv
                                              : ((unsigned)iv | 0x80000000u);
                atomicMax(&msegu[hd], key);
            }
        }
    }
    __syncthreads();                                  // B3

    float mx[4];
#pragma unroll
    for (int hd = 0; hd < 4; ++hd) {
        const unsigned key = msegu[hd];
        const int im = (key & 0x80000000u) ? (int)(key & 0x7fffffffu) : (int)~key;
        mx[hd] = __int_as_float(im);
    }

    // ---- pass B: exp + unnormalized attention row (denom folded later) -----
    {
        const bool sl = (t < 32) && (t == n);
#pragma unroll
        for (int hd = 0; hd < 4; ++hd) {
            if (ed0 == n) {
                float v = als[es0 * 4 + hd] + adn[hd];
                v = (v >= 0.f) ? v : NEG_SLOPE * v;
                atomicAdd(&M[es0 * 4 + hd], expf(v - mx[hd]));
            }
            if (ed1 == n) {
                float v = als[es1 * 4 + hd] + adn[hd];
                v = (v >= 0.f) ? v : NEG_SLOPE * v;
                atomicAdd(&M[es1 * 4 + hd], expf(v - mx[hd]));
            }
            if (sl) {
                float v = als[n * 4 + hd] + adn[hd];
                v = (v >= 0.f) ? v : NEG_SLOPE * v;
                atomicAdd(&M[n * 4 + hd], expf(v - mx[hd]));
            }
        }
    }
    __syncthreads();                                  // B4

    // ---- aggregation (W-free!): out[t] = sum_s M*hs[s][t]/sum_s M + b; SiLU
    {
        const int hd = t >> 6;
        float acc = 0.f, msum = 0.f;
#pragma unroll
        for (int s = 0; s < N_NODES; ++s) {
            const float m = M[s * 4 + hd];            // wave-uniform broadcast
            msum += m;
            acc += m * hs[s * XS + t];                // 2-way bank alias: free
        }
        const float v = acc / msum + gb;
        sv[t] = v / (1.0f + expf(-v));
    }
    __syncthreads();                                  // B5

    // ---- classifier: 8 groups x 32 cols, cls_W already in registers --------
    {
        const int j = t & 31, g = t >> 5;
        float a = 0.f;
#pragma unroll
        for (int i = 0; i < 32; ++i) a += sv[g * 32 + i] * cw[i];
        cred[g][j] = a;
    }
    __syncthreads();                                  // B6
    if (t < 32) {
        float s2 = cb;
#pragma unroll
        for (int g = 0; g < 8; ++g) s2 += cred[g][t];
        out[n * 32 + t] = s2;
    }
}

// ---------------------------------------------------------------------------
extern "C" void kernel_launch(void* const* d_in, const int* in_sizes, int n_in,
                              void* d_out, int out_size, void* d_ws, size_t ws_size,
                              hipStream_t stream) {
    const float* roi   = (const float*)d_in[0];
    const int*   eidx  = (const int*)d_in[1];
    const float* W     = (const float*)d_in[2];
    const float* a_src = (const float*)d_in[3];
    const float* a_dst = (const float*)d_in[4];
    const float* gbias = (const float*)d_in[5];
    const float* clsW  = (const float*)d_in[6];
    const float* clsb  = (const float*)d_in[7];
    float* out = (float*)d_out;

    float* x = (float*)d_ws;                   // [8192] floats
    float* H = x + 8192;                       // [8192] floats

    pool_kernel<<<(N_NODES * CDIM) / 4, 256, 0, stream>>>(roi, x);
    h_kernel<<<256, 256, 0, stream>>>(x, W, H);
    gat_kernel<<<N_NODES, 256, 0, stream>>>(eidx, H, a_src, a_dst,
                                            gbias, clsW, clsb, out);
}